// Round 12
// baseline (287.779 us; speedup 1.0000x reference)
//
#include <hip/hip_runtime.h>
#include <hip/hip_bf16.h>

// GINConv fused pipeline for MI355X (gfx950), dtype-adaptive.
// out[N,128] = x + relu( Lin2( relu( BN( Lin1( (1+eps)x + scatter_sum(x) ) ) ) ) )
// R17: R16 best (284us; bf16-gather theory confirmed, gather+gemm1 <41us).
// gemm2 (41.7us) traffic = h1 25.6 + x-residual 51.2(fp32) + out 51.2. The
// residual is the largest reducible term: xb (bf16 x) now gets a PERSISTENT
// workspace region (d_ws is 256MiB; we use ~80MB) so it survives gemm1, and
// gemm2 reads the residual as bf16 (halves that stream). k_cvt folded into
// k_detect (mode derived per-block from gamma[0]; grid-stride, 1024 blocks)
// -- one fewer launch, conversion overlaps counts-zeroing.

typedef __attribute__((ext_vector_type(8))) short short8;
typedef __attribute__((ext_vector_type(4))) float f32x4;

static __device__ __forceinline__ float bf2f(unsigned short u) {
    union { unsigned int i; float f; } z; z.i = ((unsigned int)u) << 16; return z.f;
}
static __device__ __forceinline__ unsigned short f2bf(float f) {
    unsigned int u = __float_as_uint(f);
    unsigned int lsb = (u >> 16) & 1u;
    u += 0x7fffu + lsb;            // round-to-nearest-even
    return (unsigned short)(u >> 16);
}
static __device__ __forceinline__ void atomAdd(float* p, float v) {
    __hip_atomic_fetch_add(p, v, __ATOMIC_RELAXED, __HIP_MEMORY_SCOPE_AGENT);
}
static __device__ __forceinline__ float lo16(unsigned int u) { return bf2f((unsigned short)(u & 0xffffu)); }
static __device__ __forceinline__ float hi16(unsigned int u) { return bf2f((unsigned short)(u >> 16)); }

// flags[0]: 0 = float tensors bf16, 1 = fp32.  flags[1]: 1 = edge_index int64.
// Zeros counts[N] and stats[256]; converts fp32 x -> bf16 xb (grid-stride).
__global__ __launch_bounds__(256) void k_detect(const unsigned short* __restrict__ gamma,
                                                const int* __restrict__ ei,
                                                int* __restrict__ flags,
                                                float* __restrict__ stats,
                                                int* __restrict__ counts, int N,
                                                const float* __restrict__ x,
                                                unsigned int* __restrict__ xb,
                                                int totalPairs) {
    int idx = blockIdx.x * 256 + threadIdx.x;
    if (idx < N) counts[idx] = 0;
    if (blockIdx.x == 0) {
        int t = threadIdx.x;
        if (t < 256) stats[t] = 0.0f;
        if (t == 0) {
            flags[0] = (gamma[0] == 0x3F80u) ? 0 : 1;
            int odd = ei[1] | ei[3] | ei[5] | ei[7] | ei[9] | ei[11] | ei[13] | ei[15];
            flags[1] = (odd == 0) ? 1 : 0;
        }
    }
    // mode derivable locally (no cross-block dependency on flags)
    if (gamma[0] != 0x3F80u) {
        int stride = gridDim.x * 256;
        for (int i = idx; i < totalPairs; i += stride) {
            float2 v = ((const float2*)x)[i];
            xb[i] = (unsigned int)f2bf(v.x) | ((unsigned int)f2bf(v.y) << 16);
        }
    }
}

// ---------------- degree histogram over dst ----------------
__global__ __launch_bounds__(256) void k_hist(const int* __restrict__ ei, int* __restrict__ counts,
                                              int E, const int* __restrict__ flags) {
    int e = blockIdx.x * 256 + threadIdx.x;
    if (e >= E) return;
    int dst = flags[1] ? ei[2 * E + 2 * e] : ei[E + e];
    atomicAdd(&counts[dst], 1);
}

// ---------------- two-level exclusive scan of counts[N] -> rowptr[N+1] ----------------
__global__ __launch_bounds__(256) void k_scan1(const int* __restrict__ counts, int* __restrict__ partA,
                                               int N) {
    __shared__ int sd[256];
    int t = threadIdx.x, idx = blockIdx.x * 256 + t;
    sd[t] = (idx < N) ? counts[idx] : 0;
    __syncthreads();
    for (int off = 128; off > 0; off >>= 1) {
        if (t < off) sd[t] += sd[t + off];
        __syncthreads();
    }
    if (t == 0) partA[blockIdx.x] = sd[0];
}

__global__ __launch_bounds__(512) void k_scan2(const int* __restrict__ partA, int* __restrict__ partB,
                                               int NB) {
    __shared__ int sd[512];
    int t = threadIdx.x;
    sd[t] = (t < NB) ? partA[t] : 0;
    __syncthreads();
    for (int off = 1; off < 512; off <<= 1) {
        int v = (t >= off) ? sd[t - off] : 0;
        __syncthreads();
        sd[t] += v;
        __syncthreads();
    }
    if (t < NB) partB[t] = sd[t] - partA[t];   // exclusive prefix
}

// writes rowptr[idx] (exclusive), rowptr[N]=E, and rewrites counts[idx] as cursor
__global__ __launch_bounds__(256) void k_scan3(int* __restrict__ counts, int* __restrict__ rowptr,
                                               const int* __restrict__ partB, int N) {
    __shared__ int sd[256];
    int t = threadIdx.x, idx = blockIdx.x * 256 + t;
    int c = (idx < N) ? counts[idx] : 0;
    sd[t] = c;
    __syncthreads();
    for (int off = 1; off < 256; off <<= 1) {
        int v = (t >= off) ? sd[t - off] : 0;
        __syncthreads();
        sd[t] += v;
        __syncthreads();
    }
    int offB = partB[blockIdx.x];
    int excl = offB + sd[t] - c;
    if (idx < N) {
        rowptr[idx] = excl;
        counts[idx] = excl;                    // becomes fill cursor
        if (idx == N - 1) rowptr[N] = excl + c;
    }
}

// ---------------- bucket fill: bucket[cursor[dst]++] = src ----------------
__global__ __launch_bounds__(256) void k_fill(const int* __restrict__ ei, int* __restrict__ cursor,
                                              int* __restrict__ bucket, int E,
                                              const int* __restrict__ flags) {
    int e = blockIdx.x * 256 + threadIdx.x;
    if (e >= E) return;
    int src, dst;
    if (flags[1]) { src = ei[2 * e]; dst = ei[2 * E + 2 * e]; }
    else          { src = ei[e];     dst = ei[E + e]; }
    int pos = atomicAdd(&cursor[dst], 1);
    bucket[pos] = src;
}

// ---------------- per-node gather: h0[n] = bf16( (1+eps)x[n] + sum x[bucket] ) -------
// one wave per node, lane covers 2 consecutive features. Rows ALWAYS bf16
// (xb when mode==1). Edge indices fetched by ONE lane-parallel load (64 at a
// time), broadcast via __shfl; row loads pipeline 8-deep.
__global__ __launch_bounds__(256) void k_gather(const void* __restrict__ x,
                                                const unsigned int* __restrict__ xb,
                                                const void* __restrict__ eps,
                                                const int* __restrict__ rowptr,
                                                const int* __restrict__ bucket,
                                                unsigned int* __restrict__ h0, int N,
                                                const int* __restrict__ flags) {
    int wave = threadIdx.x >> 6, lane = threadIdx.x & 63;
    int n = blockIdx.x * 4 + wave;
    if (n >= N) return;
    int mode = flags[0];
    const unsigned int* xr = mode ? xb : (const unsigned int*)x;  // 64 uints/row
    int beg = rowptr[n], end = rowptr[n + 1];
    int len = end - beg;
    float ax = 0.f, ay = 0.f;
    unsigned int su = xr[(size_t)n * 64 + lane];      // self row: issue first
    for (int base = 0; base < len; base += 64) {
        int rem = len - base; if (rem > 64) rem = 64;
        int idx = (lane < rem) ? bucket[beg + base + lane] : 0;
        int j = 0;
        for (; j + 8 <= rem; j += 8) {
            int s0 = __shfl(idx, j),     s1 = __shfl(idx, j + 1);
            int s2 = __shfl(idx, j + 2), s3 = __shfl(idx, j + 3);
            int s4 = __shfl(idx, j + 4), s5 = __shfl(idx, j + 5);
            int s6 = __shfl(idx, j + 6), s7 = __shfl(idx, j + 7);
            unsigned int u0 = xr[(size_t)s0 * 64 + lane];
            unsigned int u1 = xr[(size_t)s1 * 64 + lane];
            unsigned int u2 = xr[(size_t)s2 * 64 + lane];
            unsigned int u3 = xr[(size_t)s3 * 64 + lane];
            unsigned int u4 = xr[(size_t)s4 * 64 + lane];
            unsigned int u5 = xr[(size_t)s5 * 64 + lane];
            unsigned int u6 = xr[(size_t)s6 * 64 + lane];
            unsigned int u7 = xr[(size_t)s7 * 64 + lane];
            ax += ((lo16(u0) + lo16(u1)) + (lo16(u2) + lo16(u3)))
                + ((lo16(u4) + lo16(u5)) + (lo16(u6) + lo16(u7)));
            ay += ((hi16(u0) + hi16(u1)) + (hi16(u2) + hi16(u3)))
                + ((hi16(u4) + hi16(u5)) + (hi16(u6) + hi16(u7)));
        }
        if (j + 4 <= rem) {
            int s0 = __shfl(idx, j),     s1 = __shfl(idx, j + 1);
            int s2 = __shfl(idx, j + 2), s3 = __shfl(idx, j + 3);
            unsigned int u0 = xr[(size_t)s0 * 64 + lane];
            unsigned int u1 = xr[(size_t)s1 * 64 + lane];
            unsigned int u2 = xr[(size_t)s2 * 64 + lane];
            unsigned int u3 = xr[(size_t)s3 * 64 + lane];
            ax += (lo16(u0) + lo16(u1)) + (lo16(u2) + lo16(u3));
            ay += (hi16(u0) + hi16(u1)) + (hi16(u2) + hi16(u3));
            j += 4;
        }
        if (j + 2 <= rem) {
            int s0 = __shfl(idx, j), s1 = __shfl(idx, j + 1);
            unsigned int u0 = xr[(size_t)s0 * 64 + lane];
            unsigned int u1 = xr[(size_t)s1 * 64 + lane];
            ax += lo16(u0) + lo16(u1);
            ay += hi16(u0) + hi16(u1);
            j += 2;
        }
        if (j < rem) {
            unsigned int u = xr[(size_t)__shfl(idx, j) * 64 + lane];
            ax += lo16(u); ay += hi16(u);
        }
    }
    float s = 1.0f + (mode ? ((const float*)eps)[0]
                           : bf2f(((const unsigned short*)eps)[0]));
    ax = fmaf(s, lo16(su), ax);
    ay = fmaf(s, hi16(su), ay);
    h0[(size_t)n * 64 + lane] = (unsigned int)f2bf(ax) | ((unsigned int)f2bf(ay) << 16);
}

// Stage 128x128 weights into LDS in MFMA-fragment order:
// chunk c (0..2047): li=c&15, kg=(c>>4)&15, t=c>>8 ; n=t*16+li, k0=kg*8.
// Read in loop as Wl[(t*256 + (c4*4+q)*16 + li)*8] -> quarter-wave reads 256B
// contiguous -> conflict-free. Converts fp32 W once per block (mode==1).
static __device__ __forceinline__ void stageW(const void* W, unsigned short* Wl,
                                              int tid, int mode) {
    for (int c = tid; c < 2048; c += 256) {
        int li = c & 15, kg = (c >> 4) & 15, t = c >> 8;
        int srcOff = (t * 16 + li) * 128 + kg * 8;
        if (mode == 0) {
            *(short8*)&Wl[c * 8] = *(const short8*)((const unsigned short*)W + srcOff);
        } else {
            const float4* wf = (const float4*)((const float*)W + srcOff);
            float4 f0 = wf[0], f1 = wf[1];
            union { short8 v; unsigned short s[8]; } u;
            u.s[0] = f2bf(f0.x); u.s[1] = f2bf(f0.y); u.s[2] = f2bf(f0.z); u.s[3] = f2bf(f0.w);
            u.s[4] = f2bf(f1.x); u.s[5] = f2bf(f1.y); u.s[6] = f2bf(f1.z); u.s[7] = f2bf(f1.w);
            *(short8*)&Wl[c * 8] = u.v;
        }
    }
}

// ---------------- h1 = bf16( h0 @ W1^T + b1 ), fused BN sum/sumsq ----------------
// 64 rows/block; wave w owns one 16-row tile. A-loads issued before staging.
// BN partial sums stored per-block (coalesced, NON-atomic) -> k_reduce.
__global__ __launch_bounds__(256, 4) void k_gemm1(const unsigned short* __restrict__ h0,
                                                  const void* __restrict__ W1,
                                                  const void* __restrict__ b1,
                                                  unsigned short* __restrict__ h1,
                                                  float* __restrict__ partials,
                                                  int N, const int* __restrict__ flags) {
    __shared__ unsigned short Wl[16384];
    __shared__ float bl[128];
    __shared__ float red_s[4][128], red_s2[4][128];
    int tid = threadIdx.x;
    int mode = flags[0];
    int lane = tid & 63, wave = tid >> 6;
    int li = lane & 15, q = lane >> 4;

    int m0 = blockIdx.x * 64 + wave * 16;
    int rowA = m0 + li; if (rowA >= N) rowA = N - 1;   // clamp; stores guarded
    const unsigned short* ap = h0 + (size_t)rowA * 128 + q * 8;
    short8 av[4];
    av[0] = *(const short8*)(ap);
    av[1] = *(const short8*)(ap + 32);
    av[2] = *(const short8*)(ap + 64);
    av[3] = *(const short8*)(ap + 96);

    stageW(W1, Wl, tid, mode);
    if (tid < 128)
        bl[tid] = mode ? ((const float*)b1)[tid] : bf2f(((const unsigned short*)b1)[tid]);
    __syncthreads();

    f32x4 acc[8] = {};
#pragma unroll
    for (int c4 = 0; c4 < 4; ++c4) {
#pragma unroll
        for (int t = 0; t < 8; ++t) {
            short8 bfrag = *(const short8*)&Wl[(t * 256 + (c4 * 4 + q) * 16 + li) * 8];
            acc[t] = __builtin_amdgcn_mfma_f32_16x16x32_bf16(av[c4], bfrag, acc[t], 0, 0, 0);
        }
    }

    float s_acc[8] = {0.f, 0.f, 0.f, 0.f, 0.f, 0.f, 0.f, 0.f};
    float s2_acc[8] = {0.f, 0.f, 0.f, 0.f, 0.f, 0.f, 0.f, 0.f};
    bool full = (m0 + 16 <= N);
    if (full) {
        unsigned short* hp = h1 + (size_t)(m0 + q * 4) * 128 + li;
#pragma unroll
        for (int t = 0; t < 8; ++t) {
            float bb = bl[t * 16 + li];
#pragma unroll
            for (int r = 0; r < 4; ++r) {
                float v = acc[t][r] + bb;
                hp[(size_t)r * 128 + t * 16] = f2bf(v);
                s_acc[t] += v; s2_acc[t] += v * v;
            }
        }
    } else if (m0 < N) {
#pragma unroll
        for (int t = 0; t < 8; ++t) {
            int col = t * 16 + li;
            float bb = bl[col];
#pragma unroll
            for (int r = 0; r < 4; ++r) {
                int row = m0 + q * 4 + r;
                if (row < N) {
                    float v = acc[t][r] + bb;
                    h1[(size_t)row * 128 + col] = f2bf(v);
                    s_acc[t] += v; s2_acc[t] += v * v;
                }
            }
        }
    }
#pragma unroll
    for (int t = 0; t < 8; ++t) {
        float s = s_acc[t], s2 = s2_acc[t];
        s  += __shfl_xor(s, 16);  s  += __shfl_xor(s, 32);
        s2 += __shfl_xor(s2, 16); s2 += __shfl_xor(s2, 32);
        if (lane < 16) { red_s[wave][t * 16 + li] = s; red_s2[wave][t * 16 + li] = s2; }
    }
    __syncthreads();
    // per-block partial row: [sum(128) | ssq(128)], coalesced non-atomic store
    float pv;
    if (tid < 128) {
        pv = red_s[0][tid] + red_s[1][tid] + red_s[2][tid] + red_s[3][tid];
    } else {
        int c = tid - 128;
        pv = red_s2[0][c] + red_s2[1][c] + red_s2[2][c] + red_s2[3][c];
    }
    partials[(size_t)blockIdx.x * 256 + tid] = pv;
}

// ---------------- reduce per-block partials -> stats[256] ----------------
// 64 blocks; block j sums rows {j, j+64, ...} with coalesced loads, then one
// atomic per thread (64 per address total -> negligible serialization).
__global__ __launch_bounds__(256) void k_reduce(const float* __restrict__ partials,
                                                float* __restrict__ stats, int nb) {
    int t = threadIdx.x;
    float acc = 0.f;
    for (int b = blockIdx.x; b < nb; b += 64)
        acc += partials[(size_t)b * 256 + t];
    atomAdd(&stats[t], acc);
}

// ---------------- out = x + relu( relu(h1*a+c) @ W2^T + b2 ) ----------------
// BN fold (a,c from stats) in prologue; 64 rows/block, 1 tile/wave.
// Residual read as bf16 in BOTH modes (xb when fp32) -- halves that stream.
__global__ __launch_bounds__(256, 4) void k_gemm2(const unsigned short* __restrict__ h1,
                                                  const void* __restrict__ W2,
                                                  const void* __restrict__ b2,
                                                  const float* __restrict__ stats,
                                                  const void* __restrict__ gamma,
                                                  const void* __restrict__ beta,
                                                  const void* __restrict__ x,
                                                  const unsigned short* __restrict__ xb,
                                                  void* __restrict__ out, int N, float invN,
                                                  const int* __restrict__ flags) {
    __shared__ unsigned short Wl[16384];
    __shared__ float bl[128], al[128], cl[128];
    int tid = threadIdx.x;
    int mode = flags[0];
    int lane = tid & 63, wave = tid >> 6;
    int li = lane & 15, q = lane >> 4;

    int m0 = blockIdx.x * 64 + wave * 16;
    int rowA = m0 + li; if (rowA >= N) rowA = N - 1;
    const unsigned short* ap = h1 + (size_t)rowA * 128 + q * 8;
    short8 hv[4];
    hv[0] = *(const short8*)(ap);
    hv[1] = *(const short8*)(ap + 32);
    hv[2] = *(const short8*)(ap + 64);
    hv[3] = *(const short8*)(ap + 96);

    stageW(W2, Wl, tid, mode);
    if (tid < 128) {
        bl[tid] = mode ? ((const float*)b2)[tid] : bf2f(((const unsigned short*)b2)[tid]);
        float mean = stats[tid] * invN;
        float var = stats[128 + tid] * invN - mean * mean;
        float g  = mode ? ((const float*)gamma)[tid] : bf2f(((const unsigned short*)gamma)[tid]);
        float bt = mode ? ((const float*)beta)[tid]  : bf2f(((const unsigned short*)beta)[tid]);
        float a = g * rsqrtf(var + 1e-5f);
        al[tid] = a;
        cl[tid] = bt - mean * a;
    }
    __syncthreads();

    // BN + ReLU transform of the A fragments (in registers)
    short8 au[4];
#pragma unroll
    for (int c4 = 0; c4 < 4; ++c4) {
        int k0 = c4 * 32 + q * 8;
        union { short8 v; unsigned short s[8]; } hu; hu.v = hv[c4];
        float4 sa = *(const float4*)&al[k0];
        float4 sb = *(const float4*)&al[k0 + 4];
        float4 ca = *(const float4*)&cl[k0];
        float4 cb = *(const float4*)&cl[k0 + 4];
        union { short8 v; unsigned short s[8]; } uu;
        uu.s[0] = f2bf(fmaxf(fmaf(bf2f(hu.s[0]), sa.x, ca.x), 0.f));
        uu.s[1] = f2bf(fmaxf(fmaf(bf2f(hu.s[1]), sa.y, ca.y), 0.f));
        uu.s[2] = f2bf(fmaxf(fmaf(bf2f(hu.s[2]), sa.z, ca.z), 0.f));
        uu.s[3] = f2bf(fmaxf(fmaf(bf2f(hu.s[3]), sa.w, ca.w), 0.f));
        uu.s[4] = f2bf(fmaxf(fmaf(bf2f(hu.s[4]), sb.x, cb.x), 0.f));
        uu.s[5] = f2bf(fmaxf(fmaf(bf2f(hu.s[5]), sb.y, cb.y), 0.f));
        uu.s[6] = f2bf(fmaxf(fmaf(bf2f(hu.s[6]), sb.z, cb.z), 0.f));
        uu.s[7] = f2bf(fmaxf(fmaf(bf2f(hu.s[7]), sb.w, cb.w), 0.f));
        au[c4] = uu.v;
    }

    bool full = (m0 + 16 <= N);
    const unsigned short* resid = mode ? xb : (const unsigned short*)x;  // bf16 in both modes
    // batch the 32 residual loads BEFORE the MFMA loop: their latency
    // hides under 32 MFMAs + LDS fragment reads.
    float xv[32];
    if (full) {
        const unsigned short* xp = resid + (size_t)(m0 + q * 4) * 128 + li;
#pragma unroll
        for (int t = 0; t < 8; ++t)
#pragma unroll
            for (int r = 0; r < 4; ++r)
                xv[t * 4 + r] = bf2f(xp[(size_t)r * 128 + t * 16]);
    }

    f32x4 acc[8] = {};
#pragma unroll
    for (int c4 = 0; c4 < 4; ++c4) {
#pragma unroll
        for (int t = 0; t < 8; ++t) {
            short8 bfrag = *(const short8*)&Wl[(t * 256 + (c4 * 4 + q) * 16 + li) * 8];
            acc[t] = __builtin_amdgcn_mfma_f32_16x16x32_bf16(au[c4], bfrag, acc[t], 0, 0, 0);
        }
    }

    if (full) {
        if (mode == 0) {
            unsigned short* op = (unsigned short*)out + (size_t)(m0 + q * 4) * 128 + li;
#pragma unroll
            for (int t = 0; t < 8; ++t) {
                float bb = bl[t * 16 + li];
#pragma unroll
                for (int r = 0; r < 4; ++r)
                    op[(size_t)r * 128 + t * 16] =
                        f2bf(xv[t * 4 + r] + fmaxf(acc[t][r] + bb, 0.f));
            }
        } else {
            float* op = (float*)out + (size_t)(m0 + q * 4) * 128 + li;
#pragma unroll
            for (int t = 0; t < 8; ++t) {
                float bb = bl[t * 16 + li];
#pragma unroll
                for (int r = 0; r < 4; ++r)
                    op[(size_t)r * 128 + t * 16] =
                        xv[t * 4 + r] + fmaxf(acc[t][r] + bb, 0.f);
            }
        }
    } else if (m0 < N) {
#pragma unroll
        for (int t = 0; t < 8; ++t) {
            int col = t * 16 + li;
            float bb = bl[col];
#pragma unroll
            for (int r = 0; r < 4; ++r) {
                int row = m0 + q * 4 + r;
                if (row < N) {
                    size_t idx = (size_t)row * 128 + col;
                    float v = fmaxf(acc[t][r] + bb, 0.f);
                    float xvs = bf2f(resid[idx]);
                    if (mode == 0) {
                        ((unsigned short*)out)[idx] = f2bf(xvs + v);
                    } else {
                        ((float*)out)[idx] = xvs + v;
                    }
                }
            }
        }
    }
}

extern "C" void kernel_launch(void* const* d_in, const int* in_sizes, int n_in,
                              void* d_out, int out_size, void* d_ws, size_t ws_size,
                              hipStream_t stream) {
    const void* x     = d_in[0];
    const int*  ei    = (const int*)d_in[1];
    const void* eps   = d_in[2];
    const void* W1    = d_in[3];
    const void* b1    = d_in[4];
    const void* gamma = d_in[5];
    const void* beta  = d_in[6];
    const void* W2    = d_in[7];
    const void* b2    = d_in[8];

    int N = in_sizes[0] / 128;
    int E = in_sizes[1] / 2;

    unsigned short* h0 = (unsigned short*)d_ws;      // [N,128] bf16 agg
    unsigned short* h1 = h0 + (size_t)N * 128;       // [N,128] bf16 Lin1 out
    int* counts = (int*)(h1 + (size_t)N * 128);      // [N]  (becomes fill cursor)
    int* rowptr = counts + N;                        // [N+1]
    int* bucket = rowptr + N + 1;                    // [E]
    int* partA  = bucket + E;                        // [512]
    int* partB  = partA + 512;                       // [512]
    float* stats = (float*)(partB + 512);            // sum[128] ssq[128]
    int*   flags = (int*)(stats + 256);              // dtype flags
    unsigned short* xb = (unsigned short*)(flags + 16); // [N,128] bf16 x (persistent)

    int NB = (N + 255) / 256;                        // scan blocks (<=512)
    int EB = (E + 255) / 256;
    int mb = (N + 63) / 64;                          // gemm blocks

    // BN partials [mb][256]: reuse the counts/rowptr/bucket region (dead after
    // k_gather) when it fits; otherwise place after xb.
    size_t partials_elems = (size_t)mb * 256;
    size_t dead_elems = (size_t)N + (size_t)(N + 1) + (size_t)E;   // ints == floats
    float* partials = (partials_elems <= dead_elems) ? (float*)counts
                    : (float*)(xb + (size_t)N * 128);

    int DB = NB > 1024 ? NB : 1024;                  // detect grid (also does cvt)
    k_detect<<<DB, 256, 0, stream>>>((const unsigned short*)gamma, ei, flags, stats,
                                     counts, N, (const float*)x,
                                     (unsigned int*)xb, N * 64);
    k_hist<<<EB, 256, 0, stream>>>(ei, counts, E, flags);
    k_scan1<<<NB, 256, 0, stream>>>(counts, partA, N);
    k_scan2<<<1, 512, 0, stream>>>(partA, partB, NB);
    k_scan3<<<NB, 256, 0, stream>>>(counts, rowptr, partB, N);
    k_fill<<<EB, 256, 0, stream>>>(ei, counts, bucket, E, flags);

    k_gather<<<(N + 3) / 4, 256, 0, stream>>>(x, (const unsigned int*)xb, eps,
                                              rowptr, bucket,
                                              (unsigned int*)h0, N, flags);

    k_gemm1<<<mb, 256, 0, stream>>>(h0, W1, b1, h1, partials, N, flags);
    k_reduce<<<64, 256, 0, stream>>>(partials, stats, mb);
    k_gemm2<<<mb, 256, 0, stream>>>(h1, W2, b2, stats, gamma, beta, x, xb, d_out, N,
                                    1.0f / (float)N, flags);
}

// Round 13
// 257.925 us; speedup vs baseline: 1.1157x; 1.1157x over previous
//
#include <hip/hip_runtime.h>
#include <hip/hip_bf16.h>

// GINConv fused pipeline for MI355X (gfx950), dtype-adaptive.
// out[N,128] = x + relu( Lin2( relu( BN( Lin1( (1+eps)x + scatter_sum(x) ) ) ) ) )
// R18: k_fill was top kernel (43.5us): WRITE 36MB for a 2.4MB bucket = 15x
// write amplification from random 4B scatter + cursor atomics (0.9TB/s eff).
// hist (similar pattern) + 3 scan launches push the CSR build to ~75us.
// Replace hist+scan123+fill with a locality-binned build (no global atomics):
//   binhist: LDS hist into 1024-node bins -> blockBins (coalesced)
//   binscan: 1 block: binStart (scan of totals) + chunkOff[blk][bin]
//   binB:    pairs (src,dst) written per-(block,bin)-contiguous via LDS cursors
//   csrfill: per bin: LDS count+scan -> rowptr coalesced; bucket filled into
//            ~24KB L2-local window via LDS cursors. Global N-scan eliminated.
// counts[] dies; 10 launches -> 9. Everything else = R17 (284us best).

typedef __attribute__((ext_vector_type(8))) short short8;
typedef __attribute__((ext_vector_type(4))) float f32x4;

#define GBINS 256        // blocks for binhist/binB
#define NPB   1024       // nodes per bin (BINS = ceil(N/1024), needs N <= 1M)

static __device__ __forceinline__ float bf2f(unsigned short u) {
    union { unsigned int i; float f; } z; z.i = ((unsigned int)u) << 16; return z.f;
}
static __device__ __forceinline__ unsigned short f2bf(float f) {
    unsigned int u = __float_as_uint(f);
    unsigned int lsb = (u >> 16) & 1u;
    u += 0x7fffu + lsb;            // round-to-nearest-even
    return (unsigned short)(u >> 16);
}
static __device__ __forceinline__ void atomAdd(float* p, float v) {
    __hip_atomic_fetch_add(p, v, __ATOMIC_RELAXED, __HIP_MEMORY_SCOPE_AGENT);
}
static __device__ __forceinline__ float lo16(unsigned int u) { return bf2f((unsigned short)(u & 0xffffu)); }
static __device__ __forceinline__ float hi16(unsigned int u) { return bf2f((unsigned short)(u >> 16)); }

// exclusive scan of sh[0..1024) in place; tmp[256] scratch; 256 threads.
static __device__ __forceinline__ void scan1024(int* sh, int* tmp, int t) {
    int v0 = sh[4 * t], v1 = sh[4 * t + 1], v2 = sh[4 * t + 2], v3 = sh[4 * t + 3];
    int s = v0 + v1 + v2 + v3;
    tmp[t] = s;
    __syncthreads();
    for (int off = 1; off < 256; off <<= 1) {
        int v = (t >= off) ? tmp[t - off] : 0;
        __syncthreads();
        tmp[t] += v;
        __syncthreads();
    }
    int excl = tmp[t] - s;
    sh[4 * t]     = excl;
    sh[4 * t + 1] = excl + v0;
    sh[4 * t + 2] = excl + v0 + v1;
    sh[4 * t + 3] = excl + v0 + v1 + v2;
    __syncthreads();
}

// flags[0]: 0 = float tensors bf16, 1 = fp32.  flags[1]: 1 = edge_index int64.
// Zeros stats[256]; converts fp32 x -> bf16 xb (grid-stride).
__global__ __launch_bounds__(256) void k_detect(const unsigned short* __restrict__ gamma,
                                                const int* __restrict__ ei,
                                                int* __restrict__ flags,
                                                float* __restrict__ stats,
                                                const float* __restrict__ x,
                                                unsigned int* __restrict__ xb,
                                                int totalPairs) {
    int idx = blockIdx.x * 256 + threadIdx.x;
    if (blockIdx.x == 0) {
        int t = threadIdx.x;
        if (t < 256) stats[t] = 0.0f;
        if (t == 0) {
            flags[0] = (gamma[0] == 0x3F80u) ? 0 : 1;
            int odd = ei[1] | ei[3] | ei[5] | ei[7] | ei[9] | ei[11] | ei[13] | ei[15];
            flags[1] = (odd == 0) ? 1 : 0;
        }
    }
    if (gamma[0] != 0x3F80u) {   // mode derivable locally
        int stride = gridDim.x * 256;
        for (int i = idx; i < totalPairs; i += stride) {
            float2 v = ((const float2*)x)[i];
            xb[i] = (unsigned int)f2bf(v.x) | ((unsigned int)f2bf(v.y) << 16);
        }
    }
}

// ---------------- per-block bin histogram (LDS, no global atomics) ----------------
__global__ __launch_bounds__(256) void k_binhist(const int* __restrict__ ei, int E, int EPB,
                                                 int BINS, int* __restrict__ blockBins,
                                                 const int* __restrict__ flags) {
    __shared__ int bh[NPB];
    int blk = blockIdx.x, t = threadIdx.x;
    for (int i = t; i < BINS; i += 256) bh[i] = 0;
    __syncthreads();
    int e0 = blk * EPB, e1 = e0 + EPB; if (e1 > E) e1 = E;
    int i64 = flags[1];
    for (int e = e0 + t; e < e1; e += 256) {
        int dst = i64 ? ei[2 * E + 2 * e] : ei[E + e];
        atomicAdd(&bh[dst >> 10], 1);          // LDS atomic
    }
    __syncthreads();
    for (int i = t; i < BINS; i += 256) blockBins[blk * BINS + i] = bh[i];
}

// ---------------- binStart (scan of totals) + chunkOff[blk][bin] ----------------
__global__ __launch_bounds__(256) void k_binscan(const int* __restrict__ blockBins,
                                                 int* __restrict__ chunkOff,
                                                 int* __restrict__ binStart,
                                                 int BINS, int E) {
    __shared__ int tot[NPB];
    __shared__ int tmp[256];
    int t = threadIdx.x;
    for (int i = t; i < NPB; i += 256) tot[i] = 0;
    __syncthreads();
    for (int bin = t; bin < BINS; bin += 256) {   // coalesced: lane = bin
        int s = 0;
        for (int blk = 0; blk < GBINS; ++blk) s += blockBins[blk * BINS + bin];
        tot[bin] = s;
    }
    __syncthreads();
    scan1024(tot, tmp, t);                         // tot = exclusive prefix
    for (int bin = t; bin < BINS; bin += 256) binStart[bin] = tot[bin];
    if (t == 0) binStart[BINS] = E;
    __syncthreads();
    for (int bin = t; bin < BINS; bin += 256) {   // coalesced per iteration
        int run = tot[bin];
        for (int blk = 0; blk < GBINS; ++blk) {
            chunkOff[blk * BINS + bin] = run;
            run += blockBins[blk * BINS + bin];
        }
    }
}

// ---------------- write (src,dst) pairs grouped by bin ----------------
__global__ __launch_bounds__(256) void k_binB(const int* __restrict__ ei, int E, int EPB,
                                              int BINS, const int* __restrict__ chunkOff,
                                              int2* __restrict__ pairs,
                                              const int* __restrict__ flags) {
    __shared__ int cur[NPB];
    int blk = blockIdx.x, t = threadIdx.x;
    for (int i = t; i < BINS; i += 256) cur[i] = chunkOff[blk * BINS + i];
    __syncthreads();
    int e0 = blk * EPB, e1 = e0 + EPB; if (e1 > E) e1 = E;
    int i64 = flags[1];
    for (int e = e0 + t; e < e1; e += 256) {
        int src, dst;
        if (i64) { src = ei[2 * e]; dst = ei[2 * E + 2 * e]; }
        else     { src = ei[e];     dst = ei[E + e]; }
        int pos = atomicAdd(&cur[dst >> 10], 1);   // LDS atomic
        pairs[pos] = make_int2(src, dst);
    }
}

// ---------------- per-bin CSR: rowptr (coalesced) + bucket (L2-local) ----------------
__global__ __launch_bounds__(256) void k_csrfill(const int2* __restrict__ pairs,
                                                 const int* __restrict__ binStart,
                                                 int* __restrict__ rowptr,
                                                 int* __restrict__ bucket,
                                                 int N, int BINS) {
    __shared__ int cnt[NPB];
    __shared__ int tmp[256];
    int b = blockIdx.x, t = threadIdx.x;
    int nodeBase = b << 10;
    int nNodes = N - nodeBase; if (nNodes > NPB) nNodes = NPB;
    int eBeg = binStart[b], eEnd = binStart[b + 1];
    for (int i = t; i < NPB; i += 256) cnt[i] = 0;
    __syncthreads();
    for (int e = eBeg + t; e < eEnd; e += 256)
        atomicAdd(&cnt[pairs[e].y - nodeBase], 1);
    __syncthreads();
    scan1024(cnt, tmp, t);                 // cnt = local exclusive prefix
    for (int i = t; i < nNodes; i += 256) {
        int v = eBeg + cnt[i];
        rowptr[nodeBase + i] = v;          // coalesced
        cnt[i] = v;                        // becomes cursor
    }
    if (b == BINS - 1 && t == 0) rowptr[N] = eEnd;
    __syncthreads();
    for (int e = eBeg + t; e < eEnd; e += 256) {
        int2 p = pairs[e];
        int pos = atomicAdd(&cnt[p.y - nodeBase], 1);   // LDS atomic
        bucket[pos] = p.x;                 // ~24KB window, line-local
    }
}

// ---------------- per-node gather: h0[n] = bf16( (1+eps)x[n] + sum x[bucket] ) -------
// one wave per node, lane covers 2 consecutive features. Rows ALWAYS bf16
// (xb when mode==1). Edge indices fetched by ONE lane-parallel load (64 at a
// time), broadcast via __shfl; row loads pipeline 8-deep.
__global__ __launch_bounds__(256) void k_gather(const void* __restrict__ x,
                                                const unsigned int* __restrict__ xb,
                                                const void* __restrict__ eps,
                                                const int* __restrict__ rowptr,
                                                const int* __restrict__ bucket,
                                                unsigned int* __restrict__ h0, int N,
                                                const int* __restrict__ flags) {
    int wave = threadIdx.x >> 6, lane = threadIdx.x & 63;
    int n = blockIdx.x * 4 + wave;
    if (n >= N) return;
    int mode = flags[0];
    const unsigned int* xr = mode ? xb : (const unsigned int*)x;  // 64 uints/row
    int beg = rowptr[n], end = rowptr[n + 1];
    int len = end - beg;
    float ax = 0.f, ay = 0.f;
    unsigned int su = xr[(size_t)n * 64 + lane];      // self row: issue first
    for (int base = 0; base < len; base += 64) {
        int rem = len - base; if (rem > 64) rem = 64;
        int idx = (lane < rem) ? bucket[beg + base + lane] : 0;
        int j = 0;
        for (; j + 8 <= rem; j += 8) {
            int s0 = __shfl(idx, j),     s1 = __shfl(idx, j + 1);
            int s2 = __shfl(idx, j + 2), s3 = __shfl(idx, j + 3);
            int s4 = __shfl(idx, j + 4), s5 = __shfl(idx, j + 5);
            int s6 = __shfl(idx, j + 6), s7 = __shfl(idx, j + 7);
            unsigned int u0 = xr[(size_t)s0 * 64 + lane];
            unsigned int u1 = xr[(size_t)s1 * 64 + lane];
            unsigned int u2 = xr[(size_t)s2 * 64 + lane];
            unsigned int u3 = xr[(size_t)s3 * 64 + lane];
            unsigned int u4 = xr[(size_t)s4 * 64 + lane];
            unsigned int u5 = xr[(size_t)s5 * 64 + lane];
            unsigned int u6 = xr[(size_t)s6 * 64 + lane];
            unsigned int u7 = xr[(size_t)s7 * 64 + lane];
            ax += ((lo16(u0) + lo16(u1)) + (lo16(u2) + lo16(u3)))
                + ((lo16(u4) + lo16(u5)) + (lo16(u6) + lo16(u7)));
            ay += ((hi16(u0) + hi16(u1)) + (hi16(u2) + hi16(u3)))
                + ((hi16(u4) + hi16(u5)) + (hi16(u6) + hi16(u7)));
        }
        if (j + 4 <= rem) {
            int s0 = __shfl(idx, j),     s1 = __shfl(idx, j + 1);
            int s2 = __shfl(idx, j + 2), s3 = __shfl(idx, j + 3);
            unsigned int u0 = xr[(size_t)s0 * 64 + lane];
            unsigned int u1 = xr[(size_t)s1 * 64 + lane];
            unsigned int u2 = xr[(size_t)s2 * 64 + lane];
            unsigned int u3 = xr[(size_t)s3 * 64 + lane];
            ax += (lo16(u0) + lo16(u1)) + (lo16(u2) + lo16(u3));
            ay += (hi16(u0) + hi16(u1)) + (hi16(u2) + hi16(u3));
            j += 4;
        }
        if (j + 2 <= rem) {
            int s0 = __shfl(idx, j), s1 = __shfl(idx, j + 1);
            unsigned int u0 = xr[(size_t)s0 * 64 + lane];
            unsigned int u1 = xr[(size_t)s1 * 64 + lane];
            ax += lo16(u0) + lo16(u1);
            ay += hi16(u0) + hi16(u1);
            j += 2;
        }
        if (j < rem) {
            unsigned int u = xr[(size_t)__shfl(idx, j) * 64 + lane];
            ax += lo16(u); ay += hi16(u);
        }
    }
    float s = 1.0f + (mode ? ((const float*)eps)[0]
                           : bf2f(((const unsigned short*)eps)[0]));
    ax = fmaf(s, lo16(su), ax);
    ay = fmaf(s, hi16(su), ay);
    h0[(size_t)n * 64 + lane] = (unsigned int)f2bf(ax) | ((unsigned int)f2bf(ay) << 16);
}

// Stage 128x128 weights into LDS in MFMA-fragment order:
// chunk c (0..2047): li=c&15, kg=(c>>4)&15, t=c>>8 ; n=t*16+li, k0=kg*8.
// Converts fp32 W once per block (mode==1).
static __device__ __forceinline__ void stageW(const void* W, unsigned short* Wl,
                                              int tid, int mode) {
    for (int c = tid; c < 2048; c += 256) {
        int li = c & 15, kg = (c >> 4) & 15, t = c >> 8;
        int srcOff = (t * 16 + li) * 128 + kg * 8;
        if (mode == 0) {
            *(short8*)&Wl[c * 8] = *(const short8*)((const unsigned short*)W + srcOff);
        } else {
            const float4* wf = (const float4*)((const float*)W + srcOff);
            float4 f0 = wf[0], f1 = wf[1];
            union { short8 v; unsigned short s[8]; } u;
            u.s[0] = f2bf(f0.x); u.s[1] = f2bf(f0.y); u.s[2] = f2bf(f0.z); u.s[3] = f2bf(f0.w);
            u.s[4] = f2bf(f1.x); u.s[5] = f2bf(f1.y); u.s[6] = f2bf(f1.z); u.s[7] = f2bf(f1.w);
            *(short8*)&Wl[c * 8] = u.v;
        }
    }
}

// ---------------- h1 = bf16( h0 @ W1^T + b1 ), fused BN sum/sumsq ----------------
__global__ __launch_bounds__(256, 4) void k_gemm1(const unsigned short* __restrict__ h0,
                                                  const void* __restrict__ W1,
                                                  const void* __restrict__ b1,
                                                  unsigned short* __restrict__ h1,
                                                  float* __restrict__ partials,
                                                  int N, const int* __restrict__ flags) {
    __shared__ unsigned short Wl[16384];
    __shared__ float bl[128];
    __shared__ float red_s[4][128], red_s2[4][128];
    int tid = threadIdx.x;
    int mode = flags[0];
    int lane = tid & 63, wave = tid >> 6;
    int li = lane & 15, q = lane >> 4;

    int m0 = blockIdx.x * 64 + wave * 16;
    int rowA = m0 + li; if (rowA >= N) rowA = N - 1;   // clamp; stores guarded
    const unsigned short* ap = h0 + (size_t)rowA * 128 + q * 8;
    short8 av[4];
    av[0] = *(const short8*)(ap);
    av[1] = *(const short8*)(ap + 32);
    av[2] = *(const short8*)(ap + 64);
    av[3] = *(const short8*)(ap + 96);

    stageW(W1, Wl, tid, mode);
    if (tid < 128)
        bl[tid] = mode ? ((const float*)b1)[tid] : bf2f(((const unsigned short*)b1)[tid]);
    __syncthreads();

    f32x4 acc[8] = {};
#pragma unroll
    for (int c4 = 0; c4 < 4; ++c4) {
#pragma unroll
        for (int t = 0; t < 8; ++t) {
            short8 bfrag = *(const short8*)&Wl[(t * 256 + (c4 * 4 + q) * 16 + li) * 8];
            acc[t] = __builtin_amdgcn_mfma_f32_16x16x32_bf16(av[c4], bfrag, acc[t], 0, 0, 0);
        }
    }

    float s_acc[8] = {0.f, 0.f, 0.f, 0.f, 0.f, 0.f, 0.f, 0.f};
    float s2_acc[8] = {0.f, 0.f, 0.f, 0.f, 0.f, 0.f, 0.f, 0.f};
    bool full = (m0 + 16 <= N);
    if (full) {
        unsigned short* hp = h1 + (size_t)(m0 + q * 4) * 128 + li;
#pragma unroll
        for (int t = 0; t < 8; ++t) {
            float bb = bl[t * 16 + li];
#pragma unroll
            for (int r = 0; r < 4; ++r) {
                float v = acc[t][r] + bb;
                hp[(size_t)r * 128 + t * 16] = f2bf(v);
                s_acc[t] += v; s2_acc[t] += v * v;
            }
        }
    } else if (m0 < N) {
#pragma unroll
        for (int t = 0; t < 8; ++t) {
            int col = t * 16 + li;
            float bb = bl[col];
#pragma unroll
            for (int r = 0; r < 4; ++r) {
                int row = m0 + q * 4 + r;
                if (row < N) {
                    float v = acc[t][r] + bb;
                    h1[(size_t)row * 128 + col] = f2bf(v);
                    s_acc[t] += v; s2_acc[t] += v * v;
                }
            }
        }
    }
#pragma unroll
    for (int t = 0; t < 8; ++t) {
        float s = s_acc[t], s2 = s2_acc[t];
        s  += __shfl_xor(s, 16);  s  += __shfl_xor(s, 32);
        s2 += __shfl_xor(s2, 16); s2 += __shfl_xor(s2, 32);
        if (lane < 16) { red_s[wave][t * 16 + li] = s; red_s2[wave][t * 16 + li] = s2; }
    }
    __syncthreads();
    float pv;
    if (tid < 128) {
        pv = red_s[0][tid] + red_s[1][tid] + red_s[2][tid] + red_s[3][tid];
    } else {
        int c = tid - 128;
        pv = red_s2[0][c] + red_s2[1][c] + red_s2[2][c] + red_s2[3][c];
    }
    partials[(size_t)blockIdx.x * 256 + tid] = pv;
}

// ---------------- reduce per-block partials -> stats[256] ----------------
__global__ __launch_bounds__(256) void k_reduce(const float* __restrict__ partials,
                                                float* __restrict__ stats, int nb) {
    int t = threadIdx.x;
    float acc = 0.f;
    for (int b = blockIdx.x; b < nb; b += 64)
        acc += partials[(size_t)b * 256 + t];
    atomAdd(&stats[t], acc);
}

// ---------------- out = x + relu( relu(h1*a+c) @ W2^T + b2 ) ----------------
// Residual read as bf16 in BOTH modes (xb when fp32).
__global__ __launch_bounds__(256, 4) void k_gemm2(const unsigned short* __restrict__ h1,
                                                  const void* __restrict__ W2,
                                                  const void* __restrict__ b2,
                                                  const float* __restrict__ stats,
                                                  const void* __restrict__ gamma,
                                                  const void* __restrict__ beta,
                                                  const void* __restrict__ x,
                                                  const unsigned short* __restrict__ xb,
                                                  void* __restrict__ out, int N, float invN,
                                                  const int* __restrict__ flags) {
    __shared__ unsigned short Wl[16384];
    __shared__ float bl[128], al[128], cl[128];
    int tid = threadIdx.x;
    int mode = flags[0];
    int lane = tid & 63, wave = tid >> 6;
    int li = lane & 15, q = lane >> 4;

    int m0 = blockIdx.x * 64 + wave * 16;
    int rowA = m0 + li; if (rowA >= N) rowA = N - 1;
    const unsigned short* ap = h1 + (size_t)rowA * 128 + q * 8;
    short8 hv[4];
    hv[0] = *(const short8*)(ap);
    hv[1] = *(const short8*)(ap + 32);
    hv[2] = *(const short8*)(ap + 64);
    hv[3] = *(const short8*)(ap + 96);

    stageW(W2, Wl, tid, mode);
    if (tid < 128) {
        bl[tid] = mode ? ((const float*)b2)[tid] : bf2f(((const unsigned short*)b2)[tid]);
        float mean = stats[tid] * invN;
        float var = stats[128 + tid] * invN - mean * mean;
        float g  = mode ? ((const float*)gamma)[tid] : bf2f(((const unsigned short*)gamma)[tid]);
        float bt = mode ? ((const float*)beta)[tid]  : bf2f(((const unsigned short*)beta)[tid]);
        float a = g * rsqrtf(var + 1e-5f);
        al[tid] = a;
        cl[tid] = bt - mean * a;
    }
    __syncthreads();

    short8 au[4];
#pragma unroll
    for (int c4 = 0; c4 < 4; ++c4) {
        int k0 = c4 * 32 + q * 8;
        union { short8 v; unsigned short s[8]; } hu; hu.v = hv[c4];
        float4 sa = *(const float4*)&al[k0];
        float4 sb = *(const float4*)&al[k0 + 4];
        float4 ca = *(const float4*)&cl[k0];
        float4 cb = *(const float4*)&cl[k0 + 4];
        union { short8 v; unsigned short s[8]; } uu;
        uu.s[0] = f2bf(fmaxf(fmaf(bf2f(hu.s[0]), sa.x, ca.x), 0.f));
        uu.s[1] = f2bf(fmaxf(fmaf(bf2f(hu.s[1]), sa.y, ca.y), 0.f));
        uu.s[2] = f2bf(fmaxf(fmaf(bf2f(hu.s[2]), sa.z, ca.z), 0.f));
        uu.s[3] = f2bf(fmaxf(fmaf(bf2f(hu.s[3]), sa.w, ca.w), 0.f));
        uu.s[4] = f2bf(fmaxf(fmaf(bf2f(hu.s[4]), sb.x, cb.x), 0.f));
        uu.s[5] = f2bf(fmaxf(fmaf(bf2f(hu.s[5]), sb.y, cb.y), 0.f));
        uu.s[6] = f2bf(fmaxf(fmaf(bf2f(hu.s[6]), sb.z, cb.z), 0.f));
        uu.s[7] = f2bf(fmaxf(fmaf(bf2f(hu.s[7]), sb.w, cb.w), 0.f));
        au[c4] = uu.v;
    }

    bool full = (m0 + 16 <= N);
    const unsigned short* resid = mode ? xb : (const unsigned short*)x;  // bf16 both modes
    float xv[32];
    if (full) {
        const unsigned short* xp = resid + (size_t)(m0 + q * 4) * 128 + li;
#pragma unroll
        for (int t = 0; t < 8; ++t)
#pragma unroll
            for (int r = 0; r < 4; ++r)
                xv[t * 4 + r] = bf2f(xp[(size_t)r * 128 + t * 16]);
    }

    f32x4 acc[8] = {};
#pragma unroll
    for (int c4 = 0; c4 < 4; ++c4) {
#pragma unroll
        for (int t = 0; t < 8; ++t) {
            short8 bfrag = *(const short8*)&Wl[(t * 256 + (c4 * 4 + q) * 16 + li) * 8];
            acc[t] = __builtin_amdgcn_mfma_f32_16x16x32_bf16(au[c4], bfrag, acc[t], 0, 0, 0);
        }
    }

    if (full) {
        if (mode == 0) {
            unsigned short* op = (unsigned short*)out + (size_t)(m0 + q * 4) * 128 + li;
#pragma unroll
            for (int t = 0; t < 8; ++t) {
                float bb = bl[t * 16 + li];
#pragma unroll
                for (int r = 0; r < 4; ++r)
                    op[(size_t)r * 128 + t * 16] =
                        f2bf(xv[t * 4 + r] + fmaxf(acc[t][r] + bb, 0.f));
            }
        } else {
            float* op = (float*)out + (size_t)(m0 + q * 4) * 128 + li;
#pragma unroll
            for (int t = 0; t < 8; ++t) {
                float bb = bl[t * 16 + li];
#pragma unroll
                for (int r = 0; r < 4; ++r)
                    op[(size_t)r * 128 + t * 16] =
                        xv[t * 4 + r] + fmaxf(acc[t][r] + bb, 0.f);
            }
        }
    } else if (m0 < N) {
#pragma unroll
        for (int t = 0; t < 8; ++t) {
            int col = t * 16 + li;
            float bb = bl[col];
#pragma unroll
            for (int r = 0; r < 4; ++r) {
                int row = m0 + q * 4 + r;
                if (row < N) {
                    size_t idx = (size_t)row * 128 + col;
                    float v = fmaxf(acc[t][r] + bb, 0.f);
                    float xvs = bf2f(resid[idx]);
                    if (mode == 0) {
                        ((unsigned short*)out)[idx] = f2bf(xvs + v);
                    } else {
                        ((float*)out)[idx] = xvs + v;
                    }
                }
            }
        }
    }
}

extern "C" void kernel_launch(void* const* d_in, const int* in_sizes, int n_in,
                              void* d_out, int out_size, void* d_ws, size_t ws_size,
                              hipStream_t stream) {
    const void* x     = d_in[0];
    const int*  ei    = (const int*)d_in[1];
    const void* eps   = d_in[2];
    const void* W1    = d_in[3];
    const void* b1    = d_in[4];
    const void* gamma = d_in[5];
    const void* beta  = d_in[6];
    const void* W2    = d_in[7];
    const void* b2    = d_in[8];

    int N = in_sizes[0] / 128;
    int E = in_sizes[1] / 2;
    int BINS = (N + NPB - 1) / NPB;                  // <= 1024 for N <= 1M
    int EPB  = (E + GBINS - 1) / GBINS;

    unsigned short* h0 = (unsigned short*)d_ws;      // [N,128] bf16 agg
    unsigned short* h1 = h0 + (size_t)N * 128;       // [N,128] bf16 Lin1 out
    int* rowptr   = (int*)(h1 + (size_t)N * 128);    // [N+1]
    int* bucket   = rowptr + N + 1;                  // [E]
    int* pairsRaw = bucket + E;                      // [2E] (int2 pairs)
    int* blockBins= pairsRaw + 2 * (size_t)E;        // [GBINS*BINS]
    int* chunkOff = blockBins + (size_t)GBINS * BINS;// [GBINS*BINS]
    int* binStart = chunkOff + (size_t)GBINS * BINS; // [BINS+1]
    float* stats  = (float*)(binStart + BINS + 1);   // sum[128] ssq[128]
    int*   flags  = (int*)(stats + 256);             // dtype flags
    unsigned short* xb = (unsigned short*)(flags + 16); // [N,128] bf16 x (persistent)

    int mb = (N + 63) / 64;                          // gemm blocks
    // partials [mb][256] floats: reuse pairs region (dead after k_csrfill)
    float* partials = (float*)pairsRaw;              // mb*256 <= 2E for this problem
    if ((size_t)mb * 256 > 2 * (size_t)E)
        partials = (float*)(xb + (size_t)N * 128);   // fallback: after xb

    k_detect<<<1024, 256, 0, stream>>>((const unsigned short*)gamma, ei, flags, stats,
                                       (const float*)x, (unsigned int*)xb, N * 64);
    k_binhist<<<GBINS, 256, 0, stream>>>(ei, E, EPB, BINS, blockBins, flags);
    k_binscan<<<1, 256, 0, stream>>>(blockBins, chunkOff, binStart, BINS, E);
    k_binB<<<GBINS, 256, 0, stream>>>(ei, E, EPB, BINS, chunkOff, (int2*)pairsRaw, flags);
    k_csrfill<<<BINS, 256, 0, stream>>>((const int2*)pairsRaw, binStart, rowptr, bucket,
                                        N, BINS);

    k_gather<<<(N + 3) / 4, 256, 0, stream>>>(x, (const unsigned int*)xb, eps,
                                              rowptr, bucket,
                                              (unsigned int*)h0, N, flags);

    k_gemm1<<<mb, 256, 0, stream>>>(h0, W1, b1, h1, partials, N, flags);
    k_reduce<<<64, 256, 0, stream>>>(partials, stats, mb);
    k_gemm2<<<mb, 256, 0, stream>>>(h1, W2, b2, stats, gamma, beta, x, xb, d_out, N,
                                    1.0f / (float)N, flags);
}